// Round 10
// baseline (450.867 us; speedup 1.0000x reference)
//
#include <hip/hip_runtime.h>

// ---------------------------------------------------------------------------
// Int4 dequant-linear, int8 path:
//   1) prepass: X fp32 -> int8 per-row symmetric quant, Q nibbles -> int8 exact
//   2) 256x256 single-barrier-phase i8 MFMA GEMM (mfma_i32_16x16x64_i8, BK=128).
// Interval p = [bar; stage_p; reads_{p+1}; mma_p]: next-phase ds_reads overlap
// this phase's MFMA. Slot transitions (I3/I7) keep vmcnt(4)+double-bar.
// Round-10 fix: B-operand register DOUBLE-BUFFER (bb0/bb1). Round 9 overwrote
// the shared bb before mma(1,0) consumed the old quadrant (C++ sequential
// semantics -- no compiler renaming). A-operands were already a0/a1.
// ---------------------------------------------------------------------------

typedef _Float16 half8 __attribute__((ext_vector_type(8)));
typedef float    floatx4 __attribute__((ext_vector_type(4)));
typedef float    fvec4 __attribute__((ext_vector_type(4)));
typedef int      ivec4 __attribute__((ext_vector_type(4)));

constexpr int M_TOT   = 8192;
constexpr int N_TOT   = 11008;
constexpr int K_TOT   = 4096;
constexpr int PACKEDC = 2048;
constexpr int NKT     = K_TOT / 128;    // 32 K-tiles of BK=128 (int8)
constexpr size_t XQ_BYTES = (size_t)M_TOT * K_TOT;
constexpr size_t SM_BYTES = (size_t)M_TOT * 4;
constexpr size_t WQ_BYTES = (size_t)N_TOT * K_TOT;

#define MEMFENCE() asm volatile("" ::: "memory")
static __device__ __forceinline__ void bar() {
    MEMFENCE(); __builtin_amdgcn_s_barrier(); MEMFENCE();
}

// ---------------- prepass: X fp32 -> int8, per-row symmetric ----------------
__global__ __launch_bounds__(256)
void quant_x_kernel(const float* __restrict__ x, signed char* __restrict__ xq,
                    float* __restrict__ sm)
{
    const int row = blockIdx.x;
    const int t   = threadIdx.x;
    const float* xr = x + (size_t)row * K_TOT;

    fvec4 v[4];
    #pragma unroll
    for (int k = 0; k < 4; ++k) v[k] = ((const fvec4*)xr)[t + 256 * k];

    float mx = 0.0f;
    #pragma unroll
    for (int k = 0; k < 4; ++k)
        #pragma unroll
        for (int j = 0; j < 4; ++j) mx = fmaxf(mx, __builtin_fabsf(v[k][j]));

    #pragma unroll
    for (int off = 32; off >= 1; off >>= 1) mx = fmaxf(mx, __shfl_xor(mx, off, 64));
    __shared__ float wm[4];
    if ((t & 63) == 0) wm[t >> 6] = mx;
    __syncthreads();
    mx = fmaxf(fmaxf(wm[0], wm[1]), fmaxf(wm[2], wm[3]));
    mx = fmaxf(mx, 1e-20f);
    const float inv = 127.0f / mx;
    if (t == 0) sm[row] = mx / 127.0f;

    signed char* oq = xq + (size_t)row * K_TOT;
    #pragma unroll
    for (int k = 0; k < 4; ++k) {
        unsigned w = 0;
        #pragma unroll
        for (int j = 0; j < 4; ++j) {
            int q = (int)rintf(v[k][j] * inv);
            q = q > 127 ? 127 : (q < -127 ? -127 : q);
            w |= (unsigned)(q & 0xFF) << (8 * j);
        }
        *(unsigned*)(oq + t * 4 + 1024 * k) = w;
    }
}

// ---------------- prepass: Q nibbles -> int8 (exact, scale deferred) ----------------
// qweight: ONE packed byte per int32 element. lo=(b&15)-8 at k=2p, hi=(b>>4)-8 at 2p+1.
__global__ void quant_q_kernel(const int* __restrict__ q, signed char* __restrict__ wq, int n8) {
    const int stride = gridDim.x * blockDim.x;
    for (int i = blockIdx.x * blockDim.x + threadIdx.x; i < n8; i += stride) {
        int ow[4];
        #pragma unroll
        for (int h = 0; h < 2; ++h) {
            ivec4 d = ((const ivec4*)q)[2 * i + h];
            #pragma unroll
            for (int e = 0; e < 2; ++e) {
                const int b0 = d[2 * e], b1 = d[2 * e + 1];
                ow[2 * h + e] = (int)( (unsigned)(((b0 & 15) - 8) & 0xFF)
                                     | ((unsigned)((((b0 >> 4) & 15) - 8) & 0xFF) << 8)
                                     | ((unsigned)(((b1 & 15) - 8) & 0xFF) << 16)
                                     | ((unsigned)((((b1 >> 4) & 15) - 8) & 0xFF) << 24));
            }
        }
        *(ivec4*)(wq + (size_t)i * 16) = *(ivec4*)ow;
    }
}

// ---------------- 256x256 single-barrier-phase GEMM, i8 MFMA, BK=128 ----------------
__global__ __launch_bounds__(512, 2)
void gemm8p_i8_kernel(const signed char* __restrict__ A, const signed char* __restrict__ Bm,
                      const float* __restrict__ sm, const float* __restrict__ scale,
                      const float* __restrict__ bias, float* __restrict__ out)
{
    __shared__ signed char L[2][2][2][128 * 128];   // [slot][mat][half][rows*128B]

    const int tid  = threadIdx.x;
    const int lane = tid & 63;
    const int wave = tid >> 6;
    const int wr   = wave >> 2;
    const int wc   = wave & 3;
    const int fr   = lane & 15;
    const int kg   = lane >> 4;

    const int bid  = blockIdx.x;
    const int swz  = (bid & 7) * 172 + (bid >> 3);
    const int band = swz / 344;
    const int rr   = swz % 344;
    const int tm   = band * 8 + (rr & 7);
    const int tn   = rr >> 3;

    const int srow = lane >> 3;
    const int sg   = lane & 7;
    const int sgk  = sg ^ srow;

    const signed char* Ag = A  + (size_t)(tm * 256) * K_TOT;
    const signed char* Bg = Bm + (size_t)(tn * 256) * K_TOT;

    ivec4 acc[8][4];
    #pragma unroll
    for (int i = 0; i < 8; ++i)
        #pragma unroll
        for (int j = 0; j < 4; ++j)
            acc[i][j] = (ivec4)0;

    auto stage = [&](int slot, int mat, int half, int kt) {
        if (kt >= NKT) kt = NKT - 1;   // clamp: ledger-preserving tail (round-4 lesson)
        const signed char* gb = mat ? Bg : Ag;
        #pragma unroll
        for (int i = 0; i < 2; ++i) {
            const int row = wave * 16 + i * 8 + srow;
            const signed char* g = gb + (size_t)(half * 128 + row) * K_TOT + kt * 128 + sgk * 16;
            signed char* l = &L[slot][mat][half][row * 128 + sg * 16];
            __builtin_amdgcn_global_load_lds((const __attribute__((address_space(1))) void*)g,
                                             (__attribute__((address_space(3))) void*)l, 16, 0, 0);
        }
    };

    ivec4 a0[4][2], a1[4][2], bb0[2][2], bb1[2][2];

    auto ldA = [&](int slot, int mh, ivec4 (&d)[4][2]) {
        const char* base = (const char*)&L[slot][0][wr][0];
        #pragma unroll
        for (int m4 = 0; m4 < 4; ++m4)
            #pragma unroll
            for (int ks = 0; ks < 2; ++ks) {
                const int row = (mh * 4 + m4) * 16 + fr;
                const int off = row * 128 + ((ks * 64 + kg * 16) ^ ((fr & 7) << 4));
                d[m4][ks] = *(const ivec4*)(base + off);
            }
    };
    auto ldB = [&](int slot, int nh, ivec4 (&d)[2][2]) {
        const char* base = (const char*)&L[slot][1][wc >> 1][0];
        #pragma unroll
        for (int n2 = 0; n2 < 2; ++n2)
            #pragma unroll
            for (int ks = 0; ks < 2; ++ks) {
                const int row = (wc & 1) * 64 + (nh * 2 + n2) * 16 + fr;
                const int off = row * 128 + ((ks * 64 + kg * 16) ^ ((fr & 7) << 4));
                d[n2][ks] = *(const ivec4*)(base + off);
            }
    };
    auto mma = [&](int mh, int nh, ivec4 (&a)[4][2], ivec4 (&b)[2][2]) {
        __builtin_amdgcn_s_setprio(1);
        #pragma unroll
        for (int m4 = 0; m4 < 4; ++m4)
            #pragma unroll
            for (int n2 = 0; n2 < 2; ++n2)
                #pragma unroll
                for (int ks = 0; ks < 2; ++ks)
                    acc[mh * 4 + m4][nh * 2 + n2] = __builtin_amdgcn_mfma_i32_16x16x64_i8(
                        a[m4][ks], b[n2][ks], acc[mh * 4 + m4][nh * 2 + n2], 0, 0, 0);
        __builtin_amdgcn_s_setprio(0);
    };

    // prologue: stage tile0 (slot0) + tile1 A (slot1); guarantee slot0; issue R0
    stage(0, 0, 0, 0); stage(0, 0, 1, 0); stage(0, 1, 0, 0); stage(0, 1, 1, 0);
    stage(1, 0, 0, 1); stage(1, 0, 1, 1);
    asm volatile("s_waitcnt vmcnt(4)" ::: "memory");
    bar();
    ldA(0, 0, a0); ldB(0, 0, bb0);                  // R0 (slot0, guaranteed)

    #pragma unroll 1
    for (int it = 0; it < K_TOT / 256; ++it) {
        const int t1 = 2 * it + 1, t2 = 2 * it + 2, t3 = 2 * it + 3;
        // I0: mma Q(0,0) slot0 (a0,bb0); prefetch R1 -> a1
        bar();
        stage(1, 1, 0, t1);
        ldA(0, 1, a1);
        mma(0, 0, a0, bb0);
        // I1: mma Q(1,0) (a1,bb0); prefetch R2 -> bb1
        bar();
        stage(1, 1, 1, t1);
        ldB(0, 1, bb1);
        mma(1, 0, a1, bb0);
        // I2: mma Q(1,1) (a1,bb1)
        bar();
        stage(0, 0, 0, t2);
        mma(1, 1, a1, bb1);
        // I3: mma Q(0,1) (a0,bb1); slot transition; then R4 -> a0,bb0 (slot1)
        bar();
        stage(0, 0, 1, t2);
        mma(0, 1, a0, bb1);
        asm volatile("s_waitcnt vmcnt(4)" ::: "memory");
        bar();
        ldA(1, 0, a0); ldB(1, 0, bb0);
        // I4: mma Q(0,0) slot1 (a0,bb0); prefetch R5 -> a1
        bar();
        stage(0, 1, 0, t2);
        ldA(1, 1, a1);
        mma(0, 0, a0, bb0);
        // I5: mma Q(1,0) (a1,bb0); prefetch R6 -> bb1
        bar();
        stage(0, 1, 1, t2);
        ldB(1, 1, bb1);
        mma(1, 0, a1, bb0);
        // I6: mma Q(1,1) (a1,bb1)
        bar();
        stage(1, 0, 0, t3);
        mma(1, 1, a1, bb1);
        // I7: mma Q(0,1) (a0,bb1); slot transition; then R0 of next iter
        bar();
        stage(1, 0, 1, t3);
        mma(0, 1, a0, bb1);
        asm volatile("s_waitcnt vmcnt(4)" ::: "memory");
        bar();
        ldA(0, 0, a0); ldB(0, 0, bb0);              // next iter (harmless at tail)
    }

    asm volatile("s_waitcnt vmcnt(0)" ::: "memory");

    // epilogue: out = acc * (s_row * scale_col) + bias
    float srv[8][4];
    const float* smr = sm + tm * 256 + wr * 128 + kg * 4;
    #pragma unroll
    for (int mi = 0; mi < 8; ++mi)
        #pragma unroll
        for (int j = 0; j < 4; ++j)
            srv[mi][j] = smr[mi * 16 + j];

    #pragma unroll
    for (int ni = 0; ni < 4; ++ni) {
        const int col = tn * 256 + wc * 64 + ni * 16 + fr;
        const float s  = scale[col];
        const float bv = bias[col];
        #pragma unroll
        for (int mi = 0; mi < 8; ++mi) {
            const int row0 = tm * 256 + wr * 128 + mi * 16 + kg * 4;
            #pragma unroll
            for (int j = 0; j < 4; ++j)
                __builtin_nontemporal_store((float)acc[mi][ni][j] * (srv[mi][j] * s) + bv,
                                            out + (size_t)(row0 + j) * N_TOT + col);
        }
    }
}

// ---------------- fallback: round-1 fused fp16 kernel (known good, no ws) ----------------
constexpr int LDSS = 40;

__global__ __launch_bounds__(256, 2)
void int4lin_fused_kernel(const float* __restrict__ X,
                          const int*   __restrict__ Q,
                          const float* __restrict__ scale,
                          const float* __restrict__ bias,
                          float*       __restrict__ out)
{
    __shared__ _Float16 As[2][128][LDSS];
    __shared__ _Float16 Bs[2][128][LDSS];

    const int tid  = threadIdx.x;
    const int lane = tid & 63;
    const int bx   = blockIdx.x;
    const int by   = blockIdx.y;
    const int wave = tid >> 6;
    const int wm   = (wave >> 1) * 64;
    const int wn   = (wave & 1) * 64;
    const int fr   = lane & 15;
    const int kg   = lane >> 4;

    const int srow  = tid >> 1;
    const int shalf = tid & 1;

    const float* aptr = X + (size_t)(by * 128 + srow) * K_TOT + shalf * 16;
    const int*   bptr = Q + (size_t)(bx * 128 + srow) * PACKEDC + shalf * 8;

    floatx4 acc[4][4];
    #pragma unroll
    for (int i = 0; i < 4; ++i)
        #pragma unroll
        for (int j = 0; j < 4; ++j)
            acc[i][j] = (floatx4)0.0f;

    fvec4 araw[4];
    ivec4 braw[2];

    auto gload = [&](int kt) {
        const fvec4* ap = (const fvec4*)(aptr + (size_t)kt * 32);
        #pragma unroll
        for (int i = 0; i < 4; ++i) araw[i] = ap[i];
        const ivec4* bp = (const ivec4*)(bptr + kt * 16);
        #pragma unroll
        for (int i = 0; i < 2; ++i) braw[i] = bp[i];
    };

    auto cvt_write = [&](int buf) {
        #pragma unroll
        for (int v = 0; v < 2; ++v) {
            half8 h;
            #pragma unroll
            for (int e = 0; e < 8; ++e)
                h[e] = (_Float16)araw[v * 2 + (e >> 2)][e & 3];
            *(half8*)&As[buf][srow][shalf * 16 + v * 8] = h;
        }
        #pragma unroll
        for (int v = 0; v < 2; ++v) {
            half8 h;
            #pragma unroll
            for (int e = 0; e < 4; ++e) {
                const int b = braw[v][e];
                h[2 * e]     = (_Float16)((b & 15) - 8);
                h[2 * e + 1] = (_Float16)((b >> 4) - 8);
            }
            *(half8*)&Bs[buf][srow][shalf * 16 + v * 8] = h;
        }
    };

    gload(0);
    cvt_write(0);
    __syncthreads();

    int cur = 0;
    #pragma unroll 1
    for (int kt = 0; kt < K_TOT / 32; ++kt) {
        if (kt + 1 < K_TOT / 32) gload(kt + 1);

        half8 af[4], bf[4];
        #pragma unroll
        for (int mi = 0; mi < 4; ++mi)
            af[mi] = *(const half8*)&As[cur][wm + mi * 16 + fr][kg * 8];
        #pragma unroll
        for (int ni = 0; ni < 4; ++ni)
            bf[ni] = *(const half8*)&Bs[cur][wn + ni * 16 + fr][kg * 8];

        #pragma unroll
        for (int mi = 0; mi < 4; ++mi)
            #pragma unroll
            for (int ni = 0; ni < 4; ++ni)
                acc[mi][ni] = __builtin_amdgcn_mfma_f32_16x16x32_f16(
                    af[mi], bf[ni], acc[mi][ni], 0, 0, 0);

        if (kt + 1 < K_TOT / 32) cvt_write(cur ^ 1);
        __syncthreads();
        cur ^= 1;
    }

    #pragma unroll
    for (int ni = 0; ni < 4; ++ni) {
        const int col = bx * 128 + wn + ni * 16 + fr;
        const float s  = scale[col];
        const float bv = bias[col];
        #pragma unroll
        for (int mi = 0; mi < 4; ++mi) {
            const int row0 = by * 128 + wm + mi * 16 + kg * 4;
            #pragma unroll
            for (int j = 0; j < 4; ++j)
                out[(size_t)(row0 + j) * N_TOT + col] = acc[mi][ni][j] * s + bv;
        }
    }
}

extern "C" void kernel_launch(void* const* d_in, const int* in_sizes, int n_in,
                              void* d_out, int out_size, void* d_ws, size_t ws_size,
                              hipStream_t stream) {
    const float* x     = (const float*)d_in[0];
    const int*   q     = (const int*)d_in[1];
    const float* scale = (const float*)d_in[2];
    const float* bias  = (const float*)d_in[3];
    float*       out   = (float*)d_out;

    if (ws_size >= XQ_BYTES + SM_BYTES + WQ_BYTES) {
        signed char* xq = (signed char*)d_ws;
        float*       sm = (float*)((char*)d_ws + XQ_BYTES);
        signed char* wq = (signed char*)((char*)d_ws + XQ_BYTES + SM_BYTES);
        quant_x_kernel<<<M_TOT, 256, 0, stream>>>(x, xq, sm);
        quant_q_kernel<<<2048, 256, 0, stream>>>(q, wq, N_TOT * PACKEDC / 8);
        gemm8p_i8_kernel<<<(M_TOT / 256) * (N_TOT / 256), 512, 0, stream>>>(
            xq, wq, sm, scale, bias, out);
    } else {
        dim3 grid(N_TOT / 128, M_TOT / 128);
        int4lin_fused_kernel<<<grid, dim3(256), 0, stream>>>(x, q, scale, bias, out);
    }
}